// Round 10
// baseline (383.285 us; speedup 1.0000x reference)
//
#include <hip/hip_runtime.h>
#include <math.h>

#define NUM_PIDS 30000
#define CQ_SIZE  8192
#define BATCH    2048
#define FEAT     256
#define EPS_BN   1e-5f
#define EPS_NORM 1e-12f
#define SCALARV  30.0f

// padded column space: [0,30000) lut, [30000,30080) pad, [30080,38272) cq
#define LUT_PAD  30080
#define NCOL     38272
#define BC       128
#define LUT_TILES 235     // 30080/128
#define CT       299      // 235 lut tiles + 64 cq tiles
#define RT       16       // 2048/128 row tiles
#define NWG      (CT*RT)  // 4784 = 8*598 (XCD-divisible)
#define NB1      240      // stats blocks, 125 lut rows each (240*125 == 30000)
#define ROWS1    125
#define QPLANE   (BATCH*FEAT)   // ushorts per q plane

// workspace layout (float element offsets)
#define WS_Q1    0
#define WS_CB1   (WS_Q1 + BATCH*FEAT)
#define WS_CB2   (WS_CB1 + BATCH)
#define WS_RN2   (WS_CB2 + BATCH)          // float2 per column: {rn, cap}
#define WS_FLAGS (WS_RN2 + 2*NCOL)         // int32, lut rows only
#define WS_PSUM  (WS_FLAGS + LUT_PAD)
#define WS_PSQ   (WS_PSUM + NB1*FEAT)
#define WS_PCNT  (WS_PSQ + NB1*FEAT)
#define WS_A1    (WS_PCNT + 256)
#define WS_B1    (WS_A1 + FEAT)
#define WS_A2    (WS_B1 + FEAT)
#define WS_B2    (WS_A2 + FEAT)
#define WS_ZT    (WS_B2 + FEAT)
#define WS_PART  (WS_ZT + BATCH)           // [CT][BATCH] floats (transposed)
#define WS_LOSS8 (WS_PART + BATCH*CT)
#define WS_XH    ((WS_LOSS8 + 8 + 3) & ~3) // 16B-aligned; ushort plane
#define WS_XL    (WS_XH + NCOL*FEAT/2)
#define WS_QP    (WS_XL + NCOL*FEAT/2)     // 4 planes: q1h,q1l,q2h,q2l

typedef __bf16 bf16x8 __attribute__((ext_vector_type(8)));
typedef float  f32x4  __attribute__((ext_vector_type(4)));

__device__ __forceinline__ unsigned short f2bf(float f) {
  __bf16 h = (__bf16)f; return __builtin_bit_cast(unsigned short, h);
}
__device__ __forceinline__ float bf2f(unsigned short u) {
  __bf16 h = __builtin_bit_cast(__bf16, u); return (float)h;
}
__device__ __forceinline__ void gload_lds16(const void* g, void* l) {
  __builtin_amdgcn_global_load_lds((__attribute__((address_space(1))) void*)(g),
                                   (__attribute__((address_space(3))) void*)(l), 16, 0, 0);
}

// ---------------- stats pass 1 (single-pass: zero rows contribute 0) --------
__global__ __launch_bounds__(256) void k_stats1(const float* __restrict__ lut,
                                                float* __restrict__ ws,
                                                int* __restrict__ flags) {
  const int t = threadIdx.x;
  const int rbase = blockIdx.x * ROWS1;
  __shared__ unsigned char wz[ROWS1 * 4];
  float s = 0.f, sq = 0.f;
  for (int i = 0; i < ROWS1; ++i) {
    float v = lut[(size_t)(rbase + i) * FEAT + t];
    s += v; sq += v * v;                       // bad rows are all-zero: add 0
    unsigned long long bal = __ballot(v != 0.0f);
    if ((t & 63) == 0) wz[i * 4 + (t >> 6)] = (bal != 0ull) ? 1 : 0;
  }
  __syncthreads();
  for (int i = t; i < ROWS1; i += 256) {
    int bad = !(wz[i*4] | wz[i*4+1] | wz[i*4+2] | wz[i*4+3]);
    flags[rbase + i] = bad;
  }
  ws[WS_PSUM + blockIdx.x * FEAT + t] = s;
  ws[WS_PSQ  + blockIdx.x * FEAT + t] = sq;
  if (t == 0) {
    int cnt = 0;
    for (int i = 0; i < ROWS1; ++i)
      cnt += (wz[i*4] | wz[i*4+1] | wz[i*4+2] | wz[i*4+3]) ? 1 : 0;
    ws[WS_PCNT + blockIdx.x] = (float)cnt;
  }
}

// ---------------- stats pass 2 ----------------------------------------------
__global__ __launch_bounds__(256) void k_stats2(const float* __restrict__ bnw,
                                                const float* __restrict__ bnb,
                                                float* __restrict__ ws) {
  const int t = threadIdx.x;
  float2* rn2 = (float2*)(ws + WS_RN2);
  float s = 0.f, sq = 0.f, n = 0.f;
  for (int b = 0; b < NB1; ++b) { s += ws[WS_PSUM + b*FEAT + t]; sq += ws[WS_PSQ + b*FEAT + t]; }
  for (int b = 0; b < NB1; ++b) n += ws[WS_PCNT + b];
  float mean = s / n;
  float var = fmaxf(sq / n - mean * mean, 0.f);
  float istd_b = rsqrtf(var + EPS_BN);
  float rv1 = var * n / (n - 1.f);
  float istd_u = rsqrtf(rv1 + EPS_BN);
  float w = bnw[t], b_ = bnb[t];
  float a1 = istd_b * w, a2 = istd_u * w;
  ws[WS_A1 + t] = a1; ws[WS_B1 + t] = b_ - mean * a1;
  ws[WS_A2 + t] = a2; ws[WS_B2 + t] = b_ - mean * a2;
  if (t < (LUT_PAD - NUM_PIDS)) rn2[NUM_PIDS + t] = make_float2(0.f, -1e30f);
}

// ------- fused: raw X -> bf16 hi/lo planes + per-column {rn, cap} -----------
// one wave per padded-space row; reads each lut/cq row exactly once
__global__ __launch_bounds__(256) void k_prep(const float* __restrict__ lut,
                                              const float* __restrict__ cq,
                                              float* __restrict__ ws,
                                              unsigned short* __restrict__ xh,
                                              unsigned short* __restrict__ xl) {
  const int row = blockIdx.x * 4 + (threadIdx.x >> 6);   // 0..NCOL-1
  const int ln = threadIdx.x & 63;
  float2* rn2 = (float2*)(ws + WS_RN2);
  if (row >= NUM_PIDS && row < LUT_PAD) {                // pad rows: zero planes
    uint2 z = make_uint2(0u, 0u);
    *(uint2*)(xh + (size_t)row * FEAT + ln * 4) = z;
    *(uint2*)(xl + (size_t)row * FEAT + ln * 4) = z;
    return;                                              // rn2 set by k_stats2
  }
  const float* src; const float* av; const float* bv;
  if (row < NUM_PIDS) {
    src = lut + (size_t)row * FEAT; av = ws + WS_A1; bv = ws + WS_B1;
  } else {
    src = cq + (size_t)(row - LUT_PAD) * FEAT; av = ws + WS_A2; bv = ws + WS_B2;
  }
  float4 x = ((const float4*)src)[ln];
  float4 a = ((const float4*)av)[ln];
  float4 b = ((const float4*)bv)[ln];
  // bf16 hi/lo planes
  unsigned short h0 = f2bf(x.x), h1 = f2bf(x.y), h2 = f2bf(x.z), h3 = f2bf(x.w);
  unsigned short l0 = f2bf(x.x - bf2f(h0)), l1 = f2bf(x.y - bf2f(h1));
  unsigned short l2 = f2bf(x.z - bf2f(h2)), l3 = f2bf(x.w - bf2f(h3));
  *(uint2*)(xh + (size_t)row * FEAT + ln * 4) =
      make_uint2((unsigned)h0 | ((unsigned)h1 << 16), (unsigned)h2 | ((unsigned)h3 << 16));
  *(uint2*)(xl + (size_t)row * FEAT + ln * 4) =
      make_uint2((unsigned)l0 | ((unsigned)l1 << 16), (unsigned)l2 | ((unsigned)l3 << 16));
  // norms
  bool nz = (x.x != 0.f) || (x.y != 0.f) || (x.z != 0.f) || (x.w != 0.f);
  unsigned long long bal = __ballot(nz);
  float t0 = a.x*x.x + b.x, t1 = a.y*x.y + b.y, t2 = a.z*x.z + b.z, t3 = a.w*x.w + b.w;
  float ssum = t0*t0 + t1*t1 + t2*t2 + t3*t3;
  for (int o = 32; o; o >>= 1) ssum += __shfl_xor(ssum, o);
  if (ln == 0) {
    // bad column: raw row all-zero -> acc=0; rn=0 gives z=0, cap=-30 -> exact -30 logit
    rn2[row] = (bal == 0ull) ? make_float2(0.f, -SCALARV)
                             : make_float2(1.0f / fmaxf(sqrtf(ssum), EPS_NORM), 1e30f);
  }
}

// ---------------- qn + q1/q2 planes + per-row scalars -----------------------
__global__ __launch_bounds__(256) void k_qn(const float* __restrict__ inp,
                                            const float* __restrict__ bnw,
                                            const float* __restrict__ bnb,
                                            float* __restrict__ ws,
                                            unsigned short* __restrict__ qp) {
  const int r = blockIdx.x, t = threadIdx.x;
  const float s0 = rsqrtf(1.0f + EPS_BN);
  float v = inp[(size_t)r * FEAT + t];
  float bn = v * (bnw[t] * s0) + bnb[t];
  float x = bn * bn;
  for (int o = 32; o; o >>= 1) x += __shfl_down(x, o);
  __shared__ float w4[4];
  __shared__ float w8[8];
  if ((t & 63) == 0) w4[t >> 6] = x;
  __syncthreads();
  float nsq = w4[0] + w4[1] + w4[2] + w4[3];
  float rinv = 1.0f / fmaxf(sqrtf(nsq), EPS_NORM);
  float qn = bn * rinv;
  float y1 = qn * ws[WS_B1 + t], y2 = qn * ws[WS_B2 + t];
  for (int o = 32; o; o >>= 1) { y1 += __shfl_down(y1, o); y2 += __shfl_down(y2, o); }
  if ((t & 63) == 0) { w8[t >> 6] = y1; w8[4 + (t >> 6)] = y2; }
  float q1 = qn * ws[WS_A1 + t], q2 = qn * ws[WS_A2 + t];
  ws[WS_Q1 + (size_t)r * FEAT + t] = q1;
  size_t o1 = (size_t)r * FEAT + t;
  unsigned short h1 = f2bf(q1), h2 = f2bf(q2);
  qp[0*QPLANE + o1] = h1;
  qp[1*QPLANE + o1] = f2bf(q1 - bf2f(h1));
  qp[2*QPLANE + o1] = h2;
  qp[3*QPLANE + o1] = f2bf(q2 - bf2f(h2));
  __syncthreads();
  if (t == 0) {
    ws[WS_CB1 + r] = w8[0] + w8[1] + w8[2] + w8[3];
    ws[WS_CB2 + r] = w8[4] + w8[5] + w8[6] + w8[7];
  }
}

// -------- MFMA GEMM: X-only LDS (round-6 proven layout), Q direct-from-L2 ---
__global__ __launch_bounds__(256, 3) void k_gemm(const unsigned short* __restrict__ xh,
                                                 const unsigned short* __restrict__ xl,
                                                 const unsigned short* __restrict__ qp,
                                                 float* __restrict__ ws) {
  // XH plane at 0, XL plane at 16384; rows of 64 halves (128 B), 8 16B slots
  __shared__ __align__(16) unsigned char smem[32768];
  const int tid = threadIdx.x;
  const int w = tid >> 6, l = tid & 63;
  const int bid = blockIdx.x;
  const int sid = (bid & 7) * (NWG / 8) + (bid >> 3);   // bijective XCD swizzle
  const int colT = sid >> 4, rowT = sid & 15;
  const bool islut = colT < LUT_TILES;
  const int colbase = colT * BC;
  const int rowbase = rowT * 128;

  const unsigned short* qh = qp + (islut ? 0 : 2) * QPLANE;
  const unsigned short* ql = qh + QPLANE;

  // staging: wave w -> plane (w&1), row-half (w>>1); 8 x 16B per lane per chunk
  // lane l -> row rh*64 + 8i + (l>>3); LDS slot (l&7) holds k-chunk (l&7)^(l>>3)
  const unsigned short* sg = (w & 1) ? xl : xh;
  unsigned char* sl = smem + (w & 1) * 16384 + (w >> 1) * 8192;
  const int segc = l >> 3;
  const int kc8l = (l & 7) ^ segc;
  const unsigned short* gp =
      sg + (size_t)(colbase + (w >> 1) * 64 + segc) * FEAT + kc8l * 8;

  const int lc = l & 15, lk = l >> 4;
  const int wr = w >> 1, wc = w & 1;
  const size_t qbase = (size_t)(rowbase + wr * 64 + lc) * FEAT;

  f32x4 acc[4][4];
#pragma unroll
  for (int rf = 0; rf < 4; ++rf)
#pragma unroll
    for (int cf = 0; cf < 4; ++cf) { f32x4 z = {0.f,0.f,0.f,0.f}; acc[rf][cf] = z; }

  for (int kc = 0; kc < 4; ++kc) {
    const int kb = kc * 64;
#pragma unroll
    for (int i = 0; i < 8; ++i)
      gload_lds16(gp + (size_t)i * 8 * FEAT + kb, sl + i * 1024);
    __syncthreads();
#pragma unroll
    for (int ks = 0; ks < 2; ++ks) {
      const int kc8 = ks * 4 + lk;
      const int sA = (kc8 ^ (lc & 7)) * 16;
      bf16x8 ah[4], al[4], bh[4], bl[4];
#pragma unroll
      for (int rf = 0; rf < 4; ++rf) {             // Q fragments straight from L2
        size_t qa = qbase + rf * 16 * FEAT + kb + kc8 * 8;
        ah[rf] = *(const bf16x8*)(qh + qa);
        al[rf] = *(const bf16x8*)(ql + qa);
      }
#pragma unroll
      for (int cf = 0; cf < 4; ++cf) {
        int off = (wc * 64 + cf * 16 + lc) * 128 + sA;
        bh[cf] = *(const bf16x8*)(smem + off);
        bl[cf] = *(const bf16x8*)(smem + 16384 + off);
      }
#pragma unroll
      for (int rf = 0; rf < 4; ++rf)
#pragma unroll
        for (int cf = 0; cf < 4; ++cf) {
          acc[rf][cf] = __builtin_amdgcn_mfma_f32_16x16x32_bf16(ah[rf], bh[cf], acc[rf][cf], 0, 0, 0);
          acc[rf][cf] = __builtin_amdgcn_mfma_f32_16x16x32_bf16(ah[rf], bl[cf], acc[rf][cf], 0, 0, 0);
          acc[rf][cf] = __builtin_amdgcn_mfma_f32_16x16x32_bf16(al[rf], bh[cf], acc[rf][cf], 0, 0, 0);
        }
    }
    __syncthreads();
  }

  // epilogue: z = min(30*rn*(acc+cb), cap); sum exp(z-30) over this tile's cols
  const float* cb = ws + (islut ? WS_CB1 : WS_CB2);
  const float2* rn2 = (const float2*)(ws + WS_RN2);
  float* red = (float*)smem;   // [128][2]
#pragma unroll
  for (int rf = 0; rf < 4; ++rf) {
    float cbv[4];
#pragma unroll
    for (int r4 = 0; r4 < 4; ++r4)
      cbv[r4] = cb[rowbase + wr * 64 + rf * 16 + lk * 4 + r4];
    float part[4] = {0.f, 0.f, 0.f, 0.f};
#pragma unroll
    for (int cf = 0; cf < 4; ++cf) {
      float2 rc = rn2[colbase + wc * 64 + cf * 16 + lc];
#pragma unroll
      for (int r4 = 0; r4 < 4; ++r4) {
        float z = SCALARV * rc.x * (acc[rf][cf][r4] + cbv[r4]);
        z = fminf(z, rc.y);
        part[r4] += __expf(z - SCALARV);
      }
    }
#pragma unroll
    for (int r4 = 0; r4 < 4; ++r4) {
#pragma unroll
      for (int o = 1; o < 16; o <<= 1) part[r4] += __shfl_xor(part[r4], o);
      if (lc == 0) red[(wr * 64 + rf * 16 + lk * 4 + r4) * 2 + wc] = part[r4];
    }
  }
  __syncthreads();
  if (tid < 128) {
    float val = red[tid * 2] + red[tid * 2 + 1];
    ws[WS_PART + (size_t)colT * BATCH + rowbase + tid] = val;   // [CT][BATCH]
  }
}

// ---------------- per-row target logit --------------------------------------
__global__ __launch_bounds__(256) void k_target(const int* __restrict__ label,
                                                const float* __restrict__ lut,
                                                float* __restrict__ ws) {
  const int r = blockIdx.x, t = threadIdx.x;
  const int* flags = (const int*)(ws + WS_FLAGS);
  const float2* rn2 = (const float2*)(ws + WS_RN2);
  int y = label[r];
  if (y >= NUM_PIDS) { if (t == 0) ws[WS_ZT + r] = 0.f; return; }
  if (flags[y] == 1) { if (t == 0) ws[WS_ZT + r] = SCALARV; return; }
  float x = ws[WS_Q1 + (size_t)r * FEAT + t] * lut[(size_t)y * FEAT + t];
  for (int o = 32; o; o >>= 1) x += __shfl_down(x, o);
  __shared__ float w4[4];
  if ((t & 63) == 0) w4[t >> 6] = x;
  __syncthreads();
  if (t == 0) {
    float dot = w4[0] + w4[1] + w4[2] + w4[3];
    ws[WS_ZT + r] = SCALARV * rn2[y].x * (dot + ws[WS_CB1 + r]);
  }
}

// ---------------- merge partials -> per-block loss sums ---------------------
__global__ __launch_bounds__(256) void k_loss(const int* __restrict__ label,
                                              float* __restrict__ ws) {
  const int t = threadIdx.x;
  const int r = blockIdx.x * 256 + t;
  const int* flags = (const int*)(ws + WS_FLAGS);
  float ls = 0.f;
  int y = label[r];
  if (y < NUM_PIDS) {
    float ss = 0.f;
    const float* p = ws + WS_PART;
    for (int c = 0; c < CT; ++c) ss += p[(size_t)c * BATCH + r];   // coalesced
    if (flags[y] == 1) ss += 1.0f - __expf(-2.0f * SCALARV);
    ls = (SCALARV + __logf(ss)) - ws[WS_ZT + r];
  }
  for (int o = 32; o; o >>= 1) ls += __shfl_down(ls, o);
  __shared__ float w4[4];
  if ((t & 63) == 0) w4[t >> 6] = ls;
  __syncthreads();
  if (t == 0) ws[WS_LOSS8 + blockIdx.x] = w4[0] + w4[1] + w4[2] + w4[3];
}

__global__ void k_loss2(float* __restrict__ ws, float* __restrict__ out) {
  if (threadIdx.x == 0) {
    float s = 0.f;
    for (int i = 0; i < 8; ++i) s += ws[WS_LOSS8 + i];
    out[0] = s / (float)BATCH;
  }
}

// ------- momentum scatter: ballot bitmask, bit-exact serial recurrence ------
__global__ __launch_bounds__(256) void k_lutupd(const int* __restrict__ label,
                                                const float* __restrict__ inp,
                                                const float* __restrict__ lut,
                                                float* __restrict__ out_lut) {
  const int r = blockIdx.x, t = threadIdx.x;
  const int y = label[r];
  if (y >= NUM_PIDS) return;
  __shared__ unsigned long long mask[32];     // bit rr: label[rr]==y
  const int wv = t >> 6, ln = t & 63;
#pragma unroll
  for (int it = 0; it < 8; ++it) {
    int i = it * 256 + wv * 64 + ln;
    unsigned long long bal = __ballot(label[i] == y);
    if (ln == 0) mask[it * 4 + wv] = bal;
  }
  __syncthreads();
  const int wr_ = r >> 6, br_ = r & 63;
  unsigned long long selfbit = 1ull << br_;
  bool after = (mask[wr_] & ~((selfbit - 1) | selfbit)) != 0ull;
  for (int w2 = wr_ + 1; w2 < 32; ++w2) after = after || (mask[w2] != 0ull);
  if (after) return;                          // only last occurrence writes
  float f = lut[(size_t)y * FEAT + t];
  for (int w2 = 0; w2 <= wr_; ++w2) {
    unsigned long long m = mask[w2];
    if (w2 == wr_) m &= (selfbit - 1) | selfbit;   // bits <= r
    while (m) {
      int b = __ffsll((unsigned long long)m) - 1;
      m &= m - 1;
      int rr = w2 * 64 + b;
      f = 0.5f * f + 0.5f * inp[(size_t)rr * FEAT + t];
    }
  }
  out_lut[(size_t)y * FEAT + t] = f;
}

// ------- circular-buffer enqueue: rank via ballot popcount ------------------
__global__ __launch_bounds__(256) void k_cqupd(const int* __restrict__ label,
                                               const float* __restrict__ inp,
                                               float* __restrict__ out_cq) {
  const int r = blockIdx.x, t = threadIdx.x;
  if (label[r] != NUM_PIDS) return;
  __shared__ unsigned long long mask[32];     // bit rr: label[rr]==NUM_PIDS
  const int wv = t >> 6, ln = t & 63;
#pragma unroll
  for (int it = 0; it < 8; ++it) {
    int i = it * 256 + wv * 64 + ln;
    unsigned long long bal = __ballot(label[i] == NUM_PIDS);
    if (ln == 0) mask[it * 4 + wv] = bal;
  }
  __syncthreads();
  const int wr_ = r >> 6, br_ = r & 63;
  int rank = 0;
  for (int w2 = 0; w2 < wr_; ++w2) rank += __popcll(mask[w2]);
  rank += __popcll(mask[wr_] & ((1ull << br_) - 1ull));
  out_cq[(size_t)rank * FEAT + t] = inp[(size_t)r * FEAT + t];   // <=2048 < 8192, no wrap
}

extern "C" void kernel_launch(void* const* d_in, const int* in_sizes, int n_in,
                              void* d_out, int out_size, void* d_ws, size_t ws_size,
                              hipStream_t stream) {
  const float* inp = (const float*)d_in[0];
  const int* label = (const int*)d_in[1];
  const float* lut = (const float*)d_in[2];
  const float* cq  = (const float*)d_in[3];
  const float* bnw = (const float*)d_in[4];
  const float* bnb = (const float*)d_in[5];
  float* out = (float*)d_out;
  float* ws  = (float*)d_ws;
  int* flags = (int*)(ws + WS_FLAGS);
  unsigned short* xh = (unsigned short*)(ws + WS_XH);
  unsigned short* xl = (unsigned short*)(ws + WS_XL);
  unsigned short* qp = (unsigned short*)(ws + WS_QP);

  float* out_lut = out + 1;
  float* out_cq  = out + 1 + (size_t)NUM_PIDS * FEAT;

  hipMemcpyAsync(out_lut, lut, (size_t)NUM_PIDS * FEAT * sizeof(float),
                 hipMemcpyDeviceToDevice, stream);
  hipMemcpyAsync(out_cq, cq, (size_t)CQ_SIZE * FEAT * sizeof(float),
                 hipMemcpyDeviceToDevice, stream);

  k_stats1<<<NB1, 256, 0, stream>>>(lut, ws, flags);
  k_stats2<<<1, 256, 0, stream>>>(bnw, bnb, ws);
  k_prep<<<NCOL / 4, 256, 0, stream>>>(lut, cq, ws, xh, xl);
  k_qn<<<BATCH, 256, 0, stream>>>(inp, bnw, bnb, ws, qp);
  k_gemm<<<NWG, 256, 0, stream>>>(xh, xl, qp, ws);
  k_target<<<BATCH, 256, 0, stream>>>(label, lut, ws);
  k_loss<<<8, 256, 0, stream>>>(label, ws);
  k_loss2<<<1, 64, 0, stream>>>(ws, out);
  k_lutupd<<<BATCH, 256, 0, stream>>>(label, inp, lut, out_lut);
  k_cqupd<<<BATCH, 256, 0, stream>>>(label, inp, out_cq);
}

// Round 11
// 347.446 us; speedup vs baseline: 1.1031x; 1.1031x over previous
//
#include <hip/hip_runtime.h>
#include <math.h>

#define NUM_PIDS 30000
#define CQ_SIZE  8192
#define BATCH    2048
#define FEAT     256
#define EPS_BN   1e-5f
#define EPS_NORM 1e-12f
#define SCALARV  30.0f

// padded column space: [0,30000) lut, [30000,30080) pad, [30080,38272) cq
#define LUT_PAD  30080
#define NCOL     38272
#define BC       128
#define LUT_TILES 235     // 30080/128
#define CT       299      // 235 lut tiles + 64 cq tiles
#define RT       16       // 2048/128 row tiles
#define NWG      (CT*RT)  // 4784 = 8*598 (XCD-divisible)
#define NB1      240      // stats blocks, 125 lut rows each (240*125 == 30000)
#define ROWS1    125
#define QPLANE   (BATCH*FEAT)   // ushorts per q plane

// workspace layout (float element offsets)
#define WS_Q1    0                         // (unused, kept for layout stability)
#define WS_CB1   (WS_Q1 + BATCH*FEAT)
#define WS_CB2   (WS_CB1 + BATCH)
#define WS_RN2   (WS_CB2 + BATCH)          // float2 per column: {rn, cap}
#define WS_FLAGS (WS_RN2 + 2*NCOL)         // int32, lut rows only
#define WS_PSUM  (WS_FLAGS + LUT_PAD)
#define WS_PSQ   (WS_PSUM + NB1*FEAT)
#define WS_PCNT  (WS_PSQ + NB1*FEAT)
#define WS_A1    (WS_PCNT + 256)
#define WS_B1    (WS_A1 + FEAT)
#define WS_A2    (WS_B1 + FEAT)
#define WS_B2    (WS_A2 + FEAT)
#define WS_ZT    (WS_B2 + FEAT)
#define WS_PART  (WS_ZT + BATCH)           // [CT][BATCH] floats (transposed)
#define WS_LOSS8 (WS_PART + BATCH*CT)
#define WS_XH    ((WS_LOSS8 + 8 + 3) & ~3) // 16B-aligned; ushort plane
#define WS_XL    (WS_XH + NCOL*FEAT/2)
#define WS_QP    (WS_XL + NCOL*FEAT/2)     // 4 planes: q1h,q1l,q2h,q2l

typedef __bf16 bf16x8 __attribute__((ext_vector_type(8)));
typedef float  f32x4  __attribute__((ext_vector_type(4)));

__device__ __forceinline__ unsigned short f2bf(float f) {
  __bf16 h = (__bf16)f; return __builtin_bit_cast(unsigned short, h);
}
__device__ __forceinline__ float bf2f(unsigned short u) {
  __bf16 h = __builtin_bit_cast(__bf16, u); return (float)h;
}
__device__ __forceinline__ void gload_lds16(const void* g, void* l) {
  __builtin_amdgcn_global_load_lds((__attribute__((address_space(1))) void*)(g),
                                   (__attribute__((address_space(3))) void*)(l), 16, 0, 0);
}

// ---------------- stats pass 1 (single-pass: zero rows contribute 0) --------
__global__ __launch_bounds__(256) void k_stats1(const float* __restrict__ lut,
                                                float* __restrict__ ws,
                                                int* __restrict__ flags) {
  const int t = threadIdx.x;
  const int rbase = blockIdx.x * ROWS1;
  __shared__ unsigned char wz[ROWS1 * 4];
  float s = 0.f, sq = 0.f;
  for (int i = 0; i < ROWS1; ++i) {
    float v = lut[(size_t)(rbase + i) * FEAT + t];
    s += v; sq += v * v;                       // bad rows are all-zero: add 0
    unsigned long long bal = __ballot(v != 0.0f);
    if ((t & 63) == 0) wz[i * 4 + (t >> 6)] = (bal != 0ull) ? 1 : 0;
  }
  __syncthreads();
  for (int i = t; i < ROWS1; i += 256) {
    int bad = !(wz[i*4] | wz[i*4+1] | wz[i*4+2] | wz[i*4+3]);
    flags[rbase + i] = bad;
  }
  ws[WS_PSUM + blockIdx.x * FEAT + t] = s;
  ws[WS_PSQ  + blockIdx.x * FEAT + t] = sq;
  if (t == 0) {
    int cnt = 0;
    for (int i = 0; i < ROWS1; ++i)
      cnt += (wz[i*4] | wz[i*4+1] | wz[i*4+2] | wz[i*4+3]) ? 1 : 0;
    ws[WS_PCNT + blockIdx.x] = (float)cnt;
  }
}

// ---------------- stats pass 2 ----------------------------------------------
__global__ __launch_bounds__(256) void k_stats2(const float* __restrict__ bnw,
                                                const float* __restrict__ bnb,
                                                float* __restrict__ ws) {
  const int t = threadIdx.x;
  float2* rn2 = (float2*)(ws + WS_RN2);
  float s = 0.f, sq = 0.f, n = 0.f;
  for (int b = 0; b < NB1; ++b) { s += ws[WS_PSUM + b*FEAT + t]; sq += ws[WS_PSQ + b*FEAT + t]; }
  for (int b = 0; b < NB1; ++b) n += ws[WS_PCNT + b];
  float mean = s / n;
  float var = fmaxf(sq / n - mean * mean, 0.f);
  float istd_b = rsqrtf(var + EPS_BN);
  float rv1 = var * n / (n - 1.f);
  float istd_u = rsqrtf(rv1 + EPS_BN);
  float w = bnw[t], b_ = bnb[t];
  float a1 = istd_b * w, a2 = istd_u * w;
  ws[WS_A1 + t] = a1; ws[WS_B1 + t] = b_ - mean * a1;
  ws[WS_A2 + t] = a2; ws[WS_B2 + t] = b_ - mean * a2;
  if (t < (LUT_PAD - NUM_PIDS)) rn2[NUM_PIDS + t] = make_float2(0.f, -1e30f);
}

// ------- fused: X -> bf16 hi/lo planes + {rn,cap} + base copy to outputs ----
// one wave per padded-space row; reads each lut/cq row exactly once
__global__ __launch_bounds__(256) void k_prep(const float* __restrict__ lut,
                                              const float* __restrict__ cq,
                                              float* __restrict__ ws,
                                              unsigned short* __restrict__ xh,
                                              unsigned short* __restrict__ xl,
                                              float* __restrict__ out_lut,
                                              float* __restrict__ out_cq) {
  const int row = blockIdx.x * 4 + (threadIdx.x >> 6);   // 0..NCOL-1
  const int ln = threadIdx.x & 63;
  float2* rn2 = (float2*)(ws + WS_RN2);
  if (row >= NUM_PIDS && row < LUT_PAD) {                // pad rows: zero planes
    uint2 z = make_uint2(0u, 0u);
    *(uint2*)(xh + (size_t)row * FEAT + ln * 4) = z;
    *(uint2*)(xl + (size_t)row * FEAT + ln * 4) = z;
    return;                                              // rn2 set by k_stats2
  }
  const float* src; const float* av; const float* bv; float* dst;
  if (row < NUM_PIDS) {
    src = lut + (size_t)row * FEAT; av = ws + WS_A1; bv = ws + WS_B1;
    dst = out_lut + (size_t)row * FEAT;
  } else {
    src = cq + (size_t)(row - LUT_PAD) * FEAT; av = ws + WS_A2; bv = ws + WS_B2;
    dst = out_cq + (size_t)(row - LUT_PAD) * FEAT;
  }
  float4 x = ((const float4*)src)[ln];
  float4 a = ((const float4*)av)[ln];
  float4 b = ((const float4*)bv)[ln];
  // base copy to output (scalar stores: dst is only 4B-aligned since out+1)
  dst[ln*4+0] = x.x; dst[ln*4+1] = x.y; dst[ln*4+2] = x.z; dst[ln*4+3] = x.w;
  // bf16 hi/lo planes
  unsigned short h0 = f2bf(x.x), h1 = f2bf(x.y), h2 = f2bf(x.z), h3 = f2bf(x.w);
  unsigned short l0 = f2bf(x.x - bf2f(h0)), l1 = f2bf(x.y - bf2f(h1));
  unsigned short l2 = f2bf(x.z - bf2f(h2)), l3 = f2bf(x.w - bf2f(h3));
  *(uint2*)(xh + (size_t)row * FEAT + ln * 4) =
      make_uint2((unsigned)h0 | ((unsigned)h1 << 16), (unsigned)h2 | ((unsigned)h3 << 16));
  *(uint2*)(xl + (size_t)row * FEAT + ln * 4) =
      make_uint2((unsigned)l0 | ((unsigned)l1 << 16), (unsigned)l2 | ((unsigned)l3 << 16));
  // norms
  bool nz = (x.x != 0.f) || (x.y != 0.f) || (x.z != 0.f) || (x.w != 0.f);
  unsigned long long bal = __ballot(nz);
  float t0 = a.x*x.x + b.x, t1 = a.y*x.y + b.y, t2 = a.z*x.z + b.z, t3 = a.w*x.w + b.w;
  float ssum = t0*t0 + t1*t1 + t2*t2 + t3*t3;
  for (int o = 32; o; o >>= 1) ssum += __shfl_xor(ssum, o);
  if (ln == 0) {
    // bad column: raw row all-zero -> acc=0; rn=0 gives z=0, cap=-30 -> exact -30 logit
    rn2[row] = (bal == 0ull) ? make_float2(0.f, -SCALARV)
                             : make_float2(1.0f / fmaxf(sqrtf(ssum), EPS_NORM), 1e30f);
  }
}

// -------- qn + q1/q2 planes + per-row scalars + FUSED target logit ----------
__global__ __launch_bounds__(256) void k_qn(const float* __restrict__ inp,
                                            const float* __restrict__ bnw,
                                            const float* __restrict__ bnb,
                                            const int* __restrict__ label,
                                            const float* __restrict__ lut,
                                            float* __restrict__ ws,
                                            unsigned short* __restrict__ qp) {
  const int r = blockIdx.x, t = threadIdx.x;
  const float s0 = rsqrtf(1.0f + EPS_BN);
  float v = inp[(size_t)r * FEAT + t];
  float bn = v * (bnw[t] * s0) + bnb[t];
  float x = bn * bn;
  for (int o = 32; o; o >>= 1) x += __shfl_down(x, o);
  __shared__ float w4[4];
  __shared__ float w8[8];
  __shared__ float w4b[4];
  if ((t & 63) == 0) w4[t >> 6] = x;
  __syncthreads();
  float nsq = w4[0] + w4[1] + w4[2] + w4[3];
  float rinv = 1.0f / fmaxf(sqrtf(nsq), EPS_NORM);
  float qn = bn * rinv;
  float y1 = qn * ws[WS_B1 + t], y2 = qn * ws[WS_B2 + t];
  for (int o = 32; o; o >>= 1) { y1 += __shfl_down(y1, o); y2 += __shfl_down(y2, o); }
  if ((t & 63) == 0) { w8[t >> 6] = y1; w8[4 + (t >> 6)] = y2; }
  float q1 = qn * ws[WS_A1 + t], q2 = qn * ws[WS_A2 + t];
  size_t o1 = (size_t)r * FEAT + t;
  unsigned short h1 = f2bf(q1), h2 = f2bf(q2);
  qp[0*QPLANE + o1] = h1;
  qp[1*QPLANE + o1] = f2bf(q1 - bf2f(h1));
  qp[2*QPLANE + o1] = h2;
  qp[3*QPLANE + o1] = f2bf(q2 - bf2f(h2));
  __syncthreads();
  if (t == 0) {
    ws[WS_CB1 + r] = w8[0] + w8[1] + w8[2] + w8[3];
    ws[WS_CB2 + r] = w8[4] + w8[5] + w8[6] + w8[7];
  }
  // ---- fused target logit (was k_target; q1 still live in registers) ----
  const int* flags = (const int*)(ws + WS_FLAGS);
  const float2* rn2 = (const float2*)(ws + WS_RN2);
  int y = label[r];
  if (y >= NUM_PIDS) { if (t == 0) ws[WS_ZT + r] = 0.f; return; }
  if (flags[y] == 1) { if (t == 0) ws[WS_ZT + r] = SCALARV; return; }
  float xt = q1 * lut[(size_t)y * FEAT + t];
  for (int o = 32; o; o >>= 1) xt += __shfl_down(xt, o);
  if ((t & 63) == 0) w4b[t >> 6] = xt;
  __syncthreads();
  if (t == 0) {
    float dot = w4b[0] + w4b[1] + w4b[2] + w4b[3];
    float cb1 = w8[0] + w8[1] + w8[2] + w8[3];
    ws[WS_ZT + r] = SCALARV * rn2[y].x * (dot + cb1);
  }
}

// -------- MFMA GEMM: round-6 proven structure (drain barrier, 0 conflicts) --
__global__ __launch_bounds__(256) void k_gemm(const unsigned short* __restrict__ xh,
                                              const unsigned short* __restrict__ xl,
                                              const unsigned short* __restrict__ qp,
                                              float* __restrict__ ws) {
  __shared__ __align__(16) unsigned char smem[65536];  // XH|XL|QH|QL 16KB each
  const int tid = threadIdx.x;
  const int w = tid >> 6, l = tid & 63;
  const int bid = blockIdx.x;
  const int sid = (bid & 7) * (NWG / 8) + (bid >> 3);   // bijective XCD swizzle
  const int colT = sid >> 4, rowT = sid & 15;
  const bool islut = colT < LUT_TILES;
  const int colbase = colT * BC;
  const int rowbase = rowT * 128;

  const unsigned short* qh = qp + (islut ? 0 : 2) * QPLANE;
  const unsigned short* ql = qh + QPLANE;

  // staging geometry: lane l -> row 8i+(l>>3); LDS slot (l&7) holds k-chunk (l&7)^(l>>3)
  const int segc = l >> 3, slot = l & 7;
  const int kc8l = slot ^ segc;
  const unsigned short* gsrc;
  unsigned char* lbase;
  int gbase;
  if (w == 0)      { gsrc = xh; lbase = smem;         gbase = colbase; }
  else if (w == 1) { gsrc = xl; lbase = smem + 16384; gbase = colbase; }
  else if (w == 2) { gsrc = qh; lbase = smem + 32768; gbase = rowbase; }
  else             { gsrc = ql; lbase = smem + 49152; gbase = rowbase; }

  const int lc = l & 15, lk = l >> 4;
  const int wr = w >> 1, wc = w & 1;

  f32x4 acc[4][4];
#pragma unroll
  for (int rf = 0; rf < 4; ++rf)
#pragma unroll
    for (int cf = 0; cf < 4; ++cf) { f32x4 z = {0.f,0.f,0.f,0.f}; acc[rf][cf] = z; }

  for (int kc = 0; kc < 4; ++kc) {
    const int kb = kc * 64;
#pragma unroll
    for (int i = 0; i < 16; ++i) {
      const unsigned short* g = gsrc + (size_t)(gbase + i * 8 + segc) * FEAT + kb + kc8l * 8;
      gload_lds16(g, lbase + i * 1024);
    }
    __syncthreads();
#pragma unroll
    for (int ks = 0; ks < 2; ++ks) {
      const int kc8 = ks * 4 + lk;
      const int sA = (kc8 ^ (lc & 7)) * 16;
      bf16x8 ah[4], al[4], bh[4], bl[4];
#pragma unroll
      for (int rf = 0; rf < 4; ++rf) {
        int off = (wr * 64 + rf * 16 + lc) * 128 + sA;
        ah[rf] = *(const bf16x8*)(smem + 32768 + off);
        al[rf] = *(const bf16x8*)(smem + 49152 + off);
      }
#pragma unroll
      for (int cf = 0; cf < 4; ++cf) {
        int off = (wc * 64 + cf * 16 + lc) * 128 + sA;
        bh[cf] = *(const bf16x8*)(smem + off);
        bl[cf] = *(const bf16x8*)(smem + 16384 + off);
      }
#pragma unroll
      for (int rf = 0; rf < 4; ++rf)
#pragma unroll
        for (int cf = 0; cf < 4; ++cf) {
          acc[rf][cf] = __builtin_amdgcn_mfma_f32_16x16x32_bf16(ah[rf], bh[cf], acc[rf][cf], 0, 0, 0);
          acc[rf][cf] = __builtin_amdgcn_mfma_f32_16x16x32_bf16(ah[rf], bl[cf], acc[rf][cf], 0, 0, 0);
          acc[rf][cf] = __builtin_amdgcn_mfma_f32_16x16x32_bf16(al[rf], bh[cf], acc[rf][cf], 0, 0, 0);
        }
    }
    __syncthreads();
  }

  // epilogue: z = min(30*rn*(acc+cb), cap); sum exp(z-30) over this tile's cols
  const float* cb = ws + (islut ? WS_CB1 : WS_CB2);
  const float2* rn2 = (const float2*)(ws + WS_RN2);
  float* red = (float*)smem;   // [128][2]
#pragma unroll
  for (int rf = 0; rf < 4; ++rf) {
    float cbv[4];
#pragma unroll
    for (int r4 = 0; r4 < 4; ++r4)
      cbv[r4] = cb[rowbase + wr * 64 + rf * 16 + lk * 4 + r4];
    float part[4] = {0.f, 0.f, 0.f, 0.f};
#pragma unroll
    for (int cf = 0; cf < 4; ++cf) {
      float2 rc = rn2[colbase + wc * 64 + cf * 16 + lc];
#pragma unroll
      for (int r4 = 0; r4 < 4; ++r4) {
        float z = SCALARV * rc.x * (acc[rf][cf][r4] + cbv[r4]);
        z = fminf(z, rc.y);
        part[r4] += __expf(z - SCALARV);
      }
    }
#pragma unroll
    for (int r4 = 0; r4 < 4; ++r4) {
#pragma unroll
      for (int o = 1; o < 16; o <<= 1) part[r4] += __shfl_xor(part[r4], o);
      if (lc == 0) red[(wr * 64 + rf * 16 + lk * 4 + r4) * 2 + wc] = part[r4];
    }
  }
  __syncthreads();
  if (tid < 128) {
    float val = red[tid * 2] + red[tid * 2 + 1];
    ws[WS_PART + (size_t)colT * BATCH + rowbase + tid] = val;   // [CT][BATCH]
  }
}

// ---------------- merge partials -> per-block loss sums ---------------------
__global__ __launch_bounds__(256) void k_loss(const int* __restrict__ label,
                                              float* __restrict__ ws) {
  const int t = threadIdx.x;
  const int r = blockIdx.x * 256 + t;
  const int* flags = (const int*)(ws + WS_FLAGS);
  float ls = 0.f;
  int y = label[r];
  if (y < NUM_PIDS) {
    float ss = 0.f;
    const float* p = ws + WS_PART;
    for (int c = 0; c < CT; ++c) ss += p[(size_t)c * BATCH + r];   // coalesced
    if (flags[y] == 1) ss += 1.0f - __expf(-2.0f * SCALARV);
    ls = (SCALARV + __logf(ss)) - ws[WS_ZT + r];
  }
  for (int o = 32; o; o >>= 1) ls += __shfl_down(ls, o);
  __shared__ float w4[4];
  if ((t & 63) == 0) w4[t >> 6] = ls;
  __syncthreads();
  if (t == 0) ws[WS_LOSS8 + blockIdx.x] = w4[0] + w4[1] + w4[2] + w4[3];
}

__global__ void k_loss2(float* __restrict__ ws, float* __restrict__ out) {
  if (threadIdx.x == 0) {
    float s = 0.f;
    for (int i = 0; i < 8; ++i) s += ws[WS_LOSS8 + i];
    out[0] = s / (float)BATCH;
  }
}

// ------- fused momentum scatter + circular-buffer enqueue (ballot masks) ----
__global__ __launch_bounds__(256) void k_lutcq(const int* __restrict__ label,
                                               const float* __restrict__ inp,
                                               const float* __restrict__ lut,
                                               float* __restrict__ out_lut,
                                               float* __restrict__ out_cq) {
  const int r = blockIdx.x, t = threadIdx.x;
  const int y = label[r];
  __shared__ unsigned long long mask[32];
  const int wv = t >> 6, ln = t & 63;
  const int wr_ = r >> 6, br_ = r & 63;
  if (y < NUM_PIDS) {
    // bit rr: label[rr]==y
#pragma unroll
    for (int it = 0; it < 8; ++it) {
      int i = it * 256 + wv * 64 + ln;
      unsigned long long bal = __ballot(label[i] == y);
      if (ln == 0) mask[it * 4 + wv] = bal;
    }
    __syncthreads();
    unsigned long long selfbit = 1ull << br_;
    bool after = (mask[wr_] & ~((selfbit - 1) | selfbit)) != 0ull;
    for (int w2 = wr_ + 1; w2 < 32; ++w2) after = after || (mask[w2] != 0ull);
    if (after) return;                        // only last occurrence writes
    float f = lut[(size_t)y * FEAT + t];
    for (int w2 = 0; w2 <= wr_; ++w2) {
      unsigned long long m = mask[w2];
      if (w2 == wr_) m &= (selfbit - 1) | selfbit;   // bits <= r
      while (m) {
        int b = __ffsll((unsigned long long)m) - 1;
        m &= m - 1;
        int rr = w2 * 64 + b;
        f = 0.5f * f + 0.5f * inp[(size_t)rr * FEAT + t];
      }
    }
    out_lut[(size_t)y * FEAT + t] = f;
  } else {
    // bit rr: label[rr]==NUM_PIDS
#pragma unroll
    for (int it = 0; it < 8; ++it) {
      int i = it * 256 + wv * 64 + ln;
      unsigned long long bal = __ballot(label[i] == NUM_PIDS);
      if (ln == 0) mask[it * 4 + wv] = bal;
    }
    __syncthreads();
    int rank = 0;
    for (int w2 = 0; w2 < wr_; ++w2) rank += __popcll(mask[w2]);
    rank += __popcll(mask[wr_] & ((1ull << br_) - 1ull));
    out_cq[(size_t)rank * FEAT + t] = inp[(size_t)r * FEAT + t];  // <=2048 < 8192
  }
}

extern "C" void kernel_launch(void* const* d_in, const int* in_sizes, int n_in,
                              void* d_out, int out_size, void* d_ws, size_t ws_size,
                              hipStream_t stream) {
  const float* inp = (const float*)d_in[0];
  const int* label = (const int*)d_in[1];
  const float* lut = (const float*)d_in[2];
  const float* cq  = (const float*)d_in[3];
  const float* bnw = (const float*)d_in[4];
  const float* bnb = (const float*)d_in[5];
  float* out = (float*)d_out;
  float* ws  = (float*)d_ws;
  int* flags = (int*)(ws + WS_FLAGS);
  unsigned short* xh = (unsigned short*)(ws + WS_XH);
  unsigned short* xl = (unsigned short*)(ws + WS_XL);
  unsigned short* qp = (unsigned short*)(ws + WS_QP);

  float* out_lut = out + 1;
  float* out_cq  = out + 1 + (size_t)NUM_PIDS * FEAT;

  k_stats1<<<NB1, 256, 0, stream>>>(lut, ws, flags);
  k_stats2<<<1, 256, 0, stream>>>(bnw, bnb, ws);
  k_prep<<<NCOL / 4, 256, 0, stream>>>(lut, cq, ws, xh, xl, out_lut, out_cq);
  k_qn<<<BATCH, 256, 0, stream>>>(inp, bnw, bnb, label, lut, ws, qp);
  k_lutcq<<<BATCH, 256, 0, stream>>>(label, inp, lut, out_lut, out_cq);
  k_gemm<<<NWG, 256, 0, stream>>>(xh, xl, qp, ws);
  k_loss<<<8, 256, 0, stream>>>(label, ws);
  k_loss2<<<1, 64, 0, stream>>>(ws, out);
}

// Round 12
// 331.339 us; speedup vs baseline: 1.1568x; 1.0486x over previous
//
#include <hip/hip_runtime.h>
#include <math.h>

#define NUM_PIDS 30000
#define CQ_SIZE  8192
#define BATCH    2048
#define FEAT     256
#define EPS_BN   1e-5f
#define EPS_NORM 1e-12f
#define SCALARV  30.0f

// padded column space: [0,30000) lut, [30000,30080) pad, [30080,38272) cq
#define LUT_PAD  30080
#define NCOL     38272
#define BC       128
#define LUT_TILES 235     // 30080/128
#define CT       299      // 235 lut tiles + 64 cq tiles
#define RT       16       // 2048/128 row tiles
#define NWG      (CT*RT)  // 4784 = 8*598 (XCD-divisible)
#define NB1      600      // stats blocks, 50 lut rows each (600*50 == 30000)
#define ROWS1    50
#define QPLANE   (BATCH*FEAT)   // ushorts per q plane

// workspace layout (float element offsets)
#define WS_Q1    0                         // (unused, kept for layout stability)
#define WS_CB1   (WS_Q1 + BATCH*FEAT)
#define WS_CB2   (WS_CB1 + BATCH)
#define WS_RN2   (WS_CB2 + BATCH)          // float2 per column: {rn, cap}
#define WS_FLAGS (WS_RN2 + 2*NCOL)         // int32, lut rows only
#define WS_PSUM  (WS_FLAGS + LUT_PAD)
#define WS_PSQ   (WS_PSUM + NB1*FEAT)
#define WS_PCNT  (WS_PSQ + NB1*FEAT)
#define WS_A1    (WS_PCNT + 640)
#define WS_B1    (WS_A1 + FEAT)
#define WS_A2    (WS_B1 + FEAT)
#define WS_B2    (WS_A2 + FEAT)
#define WS_ZT    (WS_B2 + FEAT)
#define WS_PART  (WS_ZT + BATCH)           // [CT][BATCH] floats (transposed)
#define WS_LOSS8 (WS_PART + BATCH*CT)
#define WS_XH    ((WS_LOSS8 + 8 + 3) & ~3) // 16B-aligned; ushort plane
#define WS_XL    (WS_XH + NCOL*FEAT/2)
#define WS_QP    (WS_XL + NCOL*FEAT/2)     // 4 planes: q1h,q1l,q2h,q2l

typedef __bf16 bf16x8 __attribute__((ext_vector_type(8)));
typedef float  f32x16 __attribute__((ext_vector_type(16)));

__device__ __forceinline__ unsigned short f2bf(float f) {
  __bf16 h = (__bf16)f; return __builtin_bit_cast(unsigned short, h);
}
__device__ __forceinline__ float bf2f(unsigned short u) {
  __bf16 h = __builtin_bit_cast(__bf16, u); return (float)h;
}
__device__ __forceinline__ void gload_lds16(const void* g, void* l) {
  __builtin_amdgcn_global_load_lds((__attribute__((address_space(1))) void*)(g),
                                   (__attribute__((address_space(3))) void*)(l), 16, 0, 0);
}

// ---------------- stats pass 1 (single-pass: zero rows contribute 0) --------
__global__ __launch_bounds__(256) void k_stats1(const float* __restrict__ lut,
                                                float* __restrict__ ws,
                                                int* __restrict__ flags) {
  const int t = threadIdx.x;
  const int rbase = blockIdx.x * ROWS1;
  __shared__ unsigned char wz[ROWS1 * 4];
  float s = 0.f, sq = 0.f;
  for (int i = 0; i < ROWS1; ++i) {
    float v = lut[(size_t)(rbase + i) * FEAT + t];
    s += v; sq += v * v;                       // bad rows are all-zero: add 0
    unsigned long long bal = __ballot(v != 0.0f);
    if ((t & 63) == 0) wz[i * 4 + (t >> 6)] = (bal != 0ull) ? 1 : 0;
  }
  __syncthreads();
  for (int i = t; i < ROWS1; i += 256) {
    int bad = !(wz[i*4] | wz[i*4+1] | wz[i*4+2] | wz[i*4+3]);
    flags[rbase + i] = bad;
  }
  ws[WS_PSUM + blockIdx.x * FEAT + t] = s;
  ws[WS_PSQ  + blockIdx.x * FEAT + t] = sq;
  if (t == 0) {
    int cnt = 0;
    for (int i = 0; i < ROWS1; ++i)
      cnt += (wz[i*4] | wz[i*4+1] | wz[i*4+2] | wz[i*4+3]) ? 1 : 0;
    ws[WS_PCNT + blockIdx.x] = (float)cnt;
  }
}

// ------- stats pass 2: 8 blocks x 32 features, 8-way partial split ----------
__global__ __launch_bounds__(256) void k_stats2(const float* __restrict__ bnw,
                                                const float* __restrict__ bnb,
                                                float* __restrict__ ws) {
  const int fl = threadIdx.x & 31;          // feature within block
  const int p  = threadIdx.x >> 5;          // partial index 0..7
  const int f  = blockIdx.x * 32 + fl;
  float2* rn2 = (float2*)(ws + WS_RN2);
  __shared__ float ps[8][32], pq[8][32], pn[8];
  float s = 0.f, sq = 0.f, n = 0.f;
  for (int b = p; b < NB1; b += 8) {
    s  += ws[WS_PSUM + b * FEAT + f];
    sq += ws[WS_PSQ  + b * FEAT + f];
    n  += ws[WS_PCNT + b];
  }
  ps[p][fl] = s; pq[p][fl] = sq;
  if (fl == 0) pn[p] = n;
  __syncthreads();
  if (p == 0) {
    float S = 0.f, SQ = 0.f, N = 0.f;
    for (int i = 0; i < 8; ++i) { S += ps[i][fl]; SQ += pq[i][fl]; N += pn[i]; }
    float mean = S / N;
    float var = fmaxf(SQ / N - mean * mean, 0.f);
    float istd_b = rsqrtf(var + EPS_BN);
    float rv1 = var * N / (N - 1.f);
    float istd_u = rsqrtf(rv1 + EPS_BN);
    float w = bnw[f], b_ = bnb[f];
    float a1 = istd_b * w, a2 = istd_u * w;
    ws[WS_A1 + f] = a1; ws[WS_B1 + f] = b_ - mean * a1;
    ws[WS_A2 + f] = a2; ws[WS_B2 + f] = b_ - mean * a2;
  }
  if (blockIdx.x == 0 && threadIdx.x < (LUT_PAD - NUM_PIDS))
    rn2[NUM_PIDS + threadIdx.x] = make_float2(0.f, -1e30f);
}

// ------- fused: X -> bf16 hi/lo planes + {rn,cap} + base copy to outputs ----
// one wave per padded-space row; reads each lut/cq row exactly once
__global__ __launch_bounds__(256) void k_prep(const float* __restrict__ lut,
                                              const float* __restrict__ cq,
                                              float* __restrict__ ws,
                                              unsigned short* __restrict__ xh,
                                              unsigned short* __restrict__ xl,
                                              float* __restrict__ out_lut,
                                              float* __restrict__ out_cq) {
  const int row = blockIdx.x * 4 + (threadIdx.x >> 6);   // 0..NCOL-1
  const int ln = threadIdx.x & 63;
  float2* rn2 = (float2*)(ws + WS_RN2);
  if (row >= NUM_PIDS && row < LUT_PAD) {                // pad rows: zero planes
    uint2 z = make_uint2(0u, 0u);
    *(uint2*)(xh + (size_t)row * FEAT + ln * 4) = z;
    *(uint2*)(xl + (size_t)row * FEAT + ln * 4) = z;
    return;                                              // rn2 set by k_stats2
  }
  const float* src; const float* av; const float* bv; float* dst;
  if (row < NUM_PIDS) {
    src = lut + (size_t)row * FEAT; av = ws + WS_A1; bv = ws + WS_B1;
    dst = out_lut + (size_t)row * FEAT;
  } else {
    src = cq + (size_t)(row - LUT_PAD) * FEAT; av = ws + WS_A2; bv = ws + WS_B2;
    dst = out_cq + (size_t)(row - LUT_PAD) * FEAT;
  }
  float4 x = ((const float4*)src)[ln];
  float4 a = ((const float4*)av)[ln];
  float4 b = ((const float4*)bv)[ln];
  // base copy to output (scalar stores: dst is only 4B-aligned since out+1)
  dst[ln*4+0] = x.x; dst[ln*4+1] = x.y; dst[ln*4+2] = x.z; dst[ln*4+3] = x.w;
  // bf16 hi/lo planes
  unsigned short h0 = f2bf(x.x), h1 = f2bf(x.y), h2 = f2bf(x.z), h3 = f2bf(x.w);
  unsigned short l0 = f2bf(x.x - bf2f(h0)), l1 = f2bf(x.y - bf2f(h1));
  unsigned short l2 = f2bf(x.z - bf2f(h2)), l3 = f2bf(x.w - bf2f(h3));
  *(uint2*)(xh + (size_t)row * FEAT + ln * 4) =
      make_uint2((unsigned)h0 | ((unsigned)h1 << 16), (unsigned)h2 | ((unsigned)h3 << 16));
  *(uint2*)(xl + (size_t)row * FEAT + ln * 4) =
      make_uint2((unsigned)l0 | ((unsigned)l1 << 16), (unsigned)l2 | ((unsigned)l3 << 16));
  // norms
  bool nz = (x.x != 0.f) || (x.y != 0.f) || (x.z != 0.f) || (x.w != 0.f);
  unsigned long long bal = __ballot(nz);
  float t0 = a.x*x.x + b.x, t1 = a.y*x.y + b.y, t2 = a.z*x.z + b.z, t3 = a.w*x.w + b.w;
  float ssum = t0*t0 + t1*t1 + t2*t2 + t3*t3;
  for (int o = 32; o; o >>= 1) ssum += __shfl_xor(ssum, o);
  if (ln == 0) {
    // bad column: raw row all-zero -> acc=0; rn=0 gives z=0, cap=-30 -> exact -30 logit
    rn2[row] = (bal == 0ull) ? make_float2(0.f, -SCALARV)
                             : make_float2(1.0f / fmaxf(sqrtf(ssum), EPS_NORM), 1e30f);
  }
}

// -------- qn + q1/q2 planes + per-row scalars + FUSED target logit ----------
__global__ __launch_bounds__(256) void k_qn(const float* __restrict__ inp,
                                            const float* __restrict__ bnw,
                                            const float* __restrict__ bnb,
                                            const int* __restrict__ label,
                                            const float* __restrict__ lut,
                                            float* __restrict__ ws,
                                            unsigned short* __restrict__ qp) {
  const int r = blockIdx.x, t = threadIdx.x;
  const float s0 = rsqrtf(1.0f + EPS_BN);
  float v = inp[(size_t)r * FEAT + t];
  float bn = v * (bnw[t] * s0) + bnb[t];
  float x = bn * bn;
  for (int o = 32; o; o >>= 1) x += __shfl_down(x, o);
  __shared__ float w4[4];
  __shared__ float w8[8];
  __shared__ float w4b[4];
  if ((t & 63) == 0) w4[t >> 6] = x;
  __syncthreads();
  float nsq = w4[0] + w4[1] + w4[2] + w4[3];
  float rinv = 1.0f / fmaxf(sqrtf(nsq), EPS_NORM);
  float qn = bn * rinv;
  float y1 = qn * ws[WS_B1 + t], y2 = qn * ws[WS_B2 + t];
  for (int o = 32; o; o >>= 1) { y1 += __shfl_down(y1, o); y2 += __shfl_down(y2, o); }
  if ((t & 63) == 0) { w8[t >> 6] = y1; w8[4 + (t >> 6)] = y2; }
  float q1 = qn * ws[WS_A1 + t], q2 = qn * ws[WS_A2 + t];
  size_t o1 = (size_t)r * FEAT + t;
  unsigned short h1 = f2bf(q1), h2 = f2bf(q2);
  qp[0*QPLANE + o1] = h1;
  qp[1*QPLANE + o1] = f2bf(q1 - bf2f(h1));
  qp[2*QPLANE + o1] = h2;
  qp[3*QPLANE + o1] = f2bf(q2 - bf2f(h2));
  __syncthreads();
  if (t == 0) {
    ws[WS_CB1 + r] = w8[0] + w8[1] + w8[2] + w8[3];
    ws[WS_CB2 + r] = w8[4] + w8[5] + w8[6] + w8[7];
  }
  // ---- fused target logit (was k_target; q1 still live in registers) ----
  const int* flags = (const int*)(ws + WS_FLAGS);
  const float2* rn2 = (const float2*)(ws + WS_RN2);
  int y = label[r];
  if (y >= NUM_PIDS) { if (t == 0) ws[WS_ZT + r] = 0.f; return; }
  if (flags[y] == 1) { if (t == 0) ws[WS_ZT + r] = SCALARV; return; }
  float xt = q1 * lut[(size_t)y * FEAT + t];
  for (int o = 32; o; o >>= 1) xt += __shfl_down(xt, o);
  if ((t & 63) == 0) w4b[t >> 6] = xt;
  __syncthreads();
  if (t == 0) {
    float dot = w4b[0] + w4b[1] + w4b[2] + w4b[3];
    float cb1 = w8[0] + w8[1] + w8[2] + w8[3];
    ws[WS_ZT + r] = SCALARV * rn2[y].x * (dot + cb1);
  }
}

// -------- MFMA GEMM: 32x32x16 shape on the proven staging/LDS layout --------
__global__ __launch_bounds__(256) void k_gemm(const unsigned short* __restrict__ xh,
                                              const unsigned short* __restrict__ xl,
                                              const unsigned short* __restrict__ qp,
                                              float* __restrict__ ws) {
  __shared__ __align__(16) unsigned char smem[65536];  // XH|XL|QH|QL 16KB each
  const int tid = threadIdx.x;
  const int w = tid >> 6, l = tid & 63;
  const int bid = blockIdx.x;
  const int sid = (bid & 7) * (NWG / 8) + (bid >> 3);   // bijective XCD swizzle
  const int colT = sid >> 4, rowT = sid & 15;
  const bool islut = colT < LUT_TILES;
  const int colbase = colT * BC;
  const int rowbase = rowT * 128;

  const unsigned short* qh = qp + (islut ? 0 : 2) * QPLANE;
  const unsigned short* ql = qh + QPLANE;

  // staging geometry (UNCHANGED, measured conflict-free):
  // lane l -> row 8i+(l>>3); LDS slot (l&7) holds k-chunk (l&7)^(l>>3)
  const int segc = l >> 3, slot = l & 7;
  const int kc8l = slot ^ segc;
  const unsigned short* gsrc;
  unsigned char* lbase;
  int gbase;
  if (w == 0)      { gsrc = xh; lbase = smem;         gbase = colbase; }
  else if (w == 1) { gsrc = xl; lbase = smem + 16384; gbase = colbase; }
  else if (w == 2) { gsrc = qh; lbase = smem + 32768; gbase = rowbase; }
  else             { gsrc = ql; lbase = smem + 49152; gbase = rowbase; }

  const int wr = w >> 1, wc = w & 1;
  const int l31 = l & 31, lhi = l >> 5;   // 32x32 frag: row/col = l&31, k-half = l>>5

  f32x16 acc[2][2];
#pragma unroll
  for (int af = 0; af < 2; ++af)
#pragma unroll
    for (int cf = 0; cf < 2; ++cf) acc[af][cf] = (f32x16)(0.f);

  for (int kc = 0; kc < 4; ++kc) {
    const int kb = kc * 64;
#pragma unroll
    for (int i = 0; i < 16; ++i) {
      const unsigned short* g = gsrc + (size_t)(gbase + i * 8 + segc) * FEAT + kb + kc8l * 8;
      gload_lds16(g, lbase + i * 1024);
    }
    __syncthreads();
#pragma unroll
    for (int kt = 0; kt < 4; ++kt) {           // 4 k-steps of 16 within K=64
      const int kc8 = kt * 2 + lhi;            // lane's 8-half chunk index
      const int sA = (kc8 ^ (l & 7)) * 16;     // read-side swizzle (row&7 == l&7)
      bf16x8 ah[2], al[2], bh[2], bl[2];
#pragma unroll
      for (int af = 0; af < 2; ++af) {
        int off = (wr * 64 + af * 32 + l31) * 128 + sA;
        ah[af] = *(const bf16x8*)(smem + 32768 + off);
        al[af] = *(const bf16x8*)(smem + 49152 + off);
      }
#pragma unroll
      for (int cf = 0; cf < 2; ++cf) {
        int off = (wc * 64 + cf * 32 + l31) * 128 + sA;
        bh[cf] = *(const bf16x8*)(smem + off);
        bl[cf] = *(const bf16x8*)(smem + 16384 + off);
      }
#pragma unroll
      for (int af = 0; af < 2; ++af)
#pragma unroll
        for (int cf = 0; cf < 2; ++cf) {
          acc[af][cf] = __builtin_amdgcn_mfma_f32_32x32x16_bf16(ah[af], bh[cf], acc[af][cf], 0, 0, 0);
          acc[af][cf] = __builtin_amdgcn_mfma_f32_32x32x16_bf16(ah[af], bl[cf], acc[af][cf], 0, 0, 0);
          acc[af][cf] = __builtin_amdgcn_mfma_f32_32x32x16_bf16(al[af], bh[cf], acc[af][cf], 0, 0, 0);
        }
    }
    __syncthreads();
  }

  // epilogue: z = min(30*rn*(acc+cb), cap); sum exp(z-30) over this tile's cols
  // C/D layout (verified m74/m101): col = lane&31, row = (reg&3)+8*(reg>>2)+4*(lane>>5)
  const float* cb = ws + (islut ? WS_CB1 : WS_CB2);
  const float2* rn2 = (const float2*)(ws + WS_RN2);
  float* red = (float*)smem;   // [128][2]
  const int rws = rowbase + wr * 64 + 4 * lhi;
  float cbv[2][16], part[2][16];
#pragma unroll
  for (int af = 0; af < 2; ++af)
#pragma unroll
    for (int g = 0; g < 16; ++g) {
      cbv[af][g] = cb[rws + af * 32 + (g & 3) + 8 * (g >> 2)];
      part[af][g] = 0.f;
    }
#pragma unroll
  for (int cf = 0; cf < 2; ++cf) {
    float2 rc = rn2[colbase + wc * 64 + cf * 32 + l31];
#pragma unroll
    for (int af = 0; af < 2; ++af)
#pragma unroll
      for (int g = 0; g < 16; ++g) {
        float z = SCALARV * rc.x * (acc[af][cf][g] + cbv[af][g]);
        z = fminf(z, rc.y);
        part[af][g] += __expf(z - SCALARV);
      }
  }
#pragma unroll
  for (int o = 1; o < 32; o <<= 1)
#pragma unroll
    for (int af = 0; af < 2; ++af)
#pragma unroll
      for (int g = 0; g < 16; ++g)
        part[af][g] += __shfl_xor(part[af][g], o);
  if (l31 == 0) {
#pragma unroll
    for (int af = 0; af < 2; ++af)
#pragma unroll
      for (int g = 0; g < 16; ++g) {
        int rloc = wr * 64 + af * 32 + (g & 3) + 8 * (g >> 2) + 4 * lhi;
        red[rloc * 2 + wc] = part[af][g];
      }
  }
  __syncthreads();
  if (tid < 128) {
    float val = red[tid * 2] + red[tid * 2 + 1];
    ws[WS_PART + (size_t)colT * BATCH + rowbase + tid] = val;   // [CT][BATCH]
  }
}

// ---------------- merge partials -> per-block loss sums ---------------------
__global__ __launch_bounds__(256) void k_loss(const int* __restrict__ label,
                                              float* __restrict__ ws) {
  const int t = threadIdx.x;
  const int r = blockIdx.x * 256 + t;
  const int* flags = (const int*)(ws + WS_FLAGS);
  float ls = 0.f;
  int y = label[r];
  if (y < NUM_PIDS) {
    float ss = 0.f;
    const float* p = ws + WS_PART;
    for (int c = 0; c < CT; ++c) ss += p[(size_t)c * BATCH + r];   // coalesced
    if (flags[y] == 1) ss += 1.0f - __expf(-2.0f * SCALARV);
    ls = (SCALARV + __logf(ss)) - ws[WS_ZT + r];
  }
  for (int o = 32; o; o >>= 1) ls += __shfl_down(ls, o);
  __shared__ float w4[4];
  if ((t & 63) == 0) w4[t >> 6] = ls;
  __syncthreads();
  if (t == 0) ws[WS_LOSS8 + blockIdx.x] = w4[0] + w4[1] + w4[2] + w4[3];
}

__global__ void k_loss2(float* __restrict__ ws, float* __restrict__ out) {
  if (threadIdx.x == 0) {
    float s = 0.f;
    for (int i = 0; i < 8; ++i) s += ws[WS_LOSS8 + i];
    out[0] = s / (float)BATCH;
  }
}

// ------- fused momentum scatter + circular-buffer enqueue (ballot masks) ----
__global__ __launch_bounds__(256) void k_lutcq(const int* __restrict__ label,
                                               const float* __restrict__ inp,
                                               const float* __restrict__ lut,
                                               float* __restrict__ out_lut,
                                               float* __restrict__ out_cq) {
  const int r = blockIdx.x, t = threadIdx.x;
  const int y = label[r];
  __shared__ unsigned long long mask[32];
  const int wv = t >> 6, ln = t & 63;
  const int wr_ = r >> 6, br_ = r & 63;
  if (y < NUM_PIDS) {
    // bit rr: label[rr]==y
#pragma unroll
    for (int it = 0; it < 8; ++it) {
      int i = it * 256 + wv * 64 + ln;
      unsigned long long bal = __ballot(label[i] == y);
      if (ln == 0) mask[it * 4 + wv] = bal;
    }
    __syncthreads();
    unsigned long long selfbit = 1ull << br_;
    bool after = (mask[wr_] & ~((selfbit - 1) | selfbit)) != 0ull;
    for (int w2 = wr_ + 1; w2 < 32; ++w2) after = after || (mask[w2] != 0ull);
    if (after) return;                        // only last occurrence writes
    float f = lut[(size_t)y * FEAT + t];
    for (int w2 = 0; w2 <= wr_; ++w2) {
      unsigned long long m = mask[w2];
      if (w2 == wr_) m &= (selfbit - 1) | selfbit;   // bits <= r
      while (m) {
        int b = __ffsll((unsigned long long)m) - 1;
        m &= m - 1;
        int rr = w2 * 64 + b;
        f = 0.5f * f + 0.5f * inp[(size_t)rr * FEAT + t];
      }
    }
    out_lut[(size_t)y * FEAT + t] = f;
  } else {
    // bit rr: label[rr]==NUM_PIDS
#pragma unroll
    for (int it = 0; it < 8; ++it) {
      int i = it * 256 + wv * 64 + ln;
      unsigned long long bal = __ballot(label[i] == NUM_PIDS);
      if (ln == 0) mask[it * 4 + wv] = bal;
    }
    __syncthreads();
    int rank = 0;
    for (int w2 = 0; w2 < wr_; ++w2) rank += __popcll(mask[w2]);
    rank += __popcll(mask[wr_] & ((1ull << br_) - 1ull));
    out_cq[(size_t)rank * FEAT + t] = inp[(size_t)r * FEAT + t];  // <=2048 < 8192
  }
}

extern "C" void kernel_launch(void* const* d_in, const int* in_sizes, int n_in,
                              void* d_out, int out_size, void* d_ws, size_t ws_size,
                              hipStream_t stream) {
  const float* inp = (const float*)d_in[0];
  const int* label = (const int*)d_in[1];
  const float* lut = (const float*)d_in[2];
  const float* cq  = (const float*)d_in[3];
  const float* bnw = (const float*)d_in[4];
  const float* bnb = (const float*)d_in[5];
  float* out = (float*)d_out;
  float* ws  = (float*)d_ws;
  int* flags = (int*)(ws + WS_FLAGS);
  unsigned short* xh = (unsigned short*)(ws + WS_XH);
  unsigned short* xl = (unsigned short*)(ws + WS_XL);
  unsigned short* qp = (unsigned short*)(ws + WS_QP);

  float* out_lut = out + 1;
  float* out_cq  = out + 1 + (size_t)NUM_PIDS * FEAT;

  k_stats1<<<NB1, 256, 0, stream>>>(lut, ws, flags);
  k_stats2<<<8, 256, 0, stream>>>(bnw, bnb, ws);
  k_prep<<<NCOL / 4, 256, 0, stream>>>(lut, cq, ws, xh, xl, out_lut, out_cq);
  k_qn<<<BATCH, 256, 0, stream>>>(inp, bnw, bnb, label, lut, ws, qp);
  k_lutcq<<<BATCH, 256, 0, stream>>>(label, inp, lut, out_lut, out_cq);
  k_gemm<<<NWG, 256, 0, stream>>>(xh, xl, qp, ws);
  k_loss<<<8, 256, 0, stream>>>(label, ws);
  k_loss2<<<1, 64, 0, stream>>>(ws, out);
}